// Round 1
// baseline (102.318 us; speedup 1.0000x reference)
//
#include <hip/hip_runtime.h>

// SKA: out[b, i*32+g, h, w] = sum_{di,dj} x[b, i*32+g, h+di-1, w+dj-1] * w[b, g, 3*di+dj, h, w]
// x: (8,256,56,56) f32, w: (8,32,9,56,56) f32, out: (8,256,56,56) f32

#define B_DIM 8
#define C_DIM 256
#define G_DIM 32
#define CPG 8          // channels per group = 256/32
#define H_DIM 56
#define W_DIM 56
#define HW 3136        // 56*56
#define SLICES 7       // spatial slices per (b,g) plane; 7*448 = 3136

__global__ __launch_bounds__(256) void SKA_20950850470021_kernel(
    const float* __restrict__ x, const float* __restrict__ wt,
    float* __restrict__ out) {
  const int bg = blockIdx.x;           // 0..255 : b*32 + g
  const int b  = bg >> 5;
  const int g  = bg & 31;

  const float* wbase = wt + (size_t)bg * 9 * HW;                 // w[b,g,0,0,0]
  const float* xbase = x  + ((size_t)b * C_DIM + g) * HW;        // x[b,g,0,0]
  float*       obase = out + ((size_t)b * C_DIM + g) * HW;

  const int p0 = blockIdx.y * 448;
  for (int p = p0 + threadIdx.x; p < p0 + 448; p += 256) {
    const int h  = p / W_DIM;
    const int wp = p - h * W_DIM;

    // Load the 9 per-pixel kernel weights once; reused across 8 channels.
    float wk[9];
#pragma unroll
    for (int k = 0; k < 9; ++k) wk[k] = wbase[(size_t)k * HW + p];

#pragma unroll
    for (int i = 0; i < CPG; ++i) {
      const float* xc = xbase + (size_t)(i * G_DIM) * HW;
      float acc = 0.f;
#pragma unroll
      for (int di = 0; di < 3; ++di) {
        const int hh = h + di - 1;
        const bool hok = (unsigned)hh < (unsigned)H_DIM;
#pragma unroll
        for (int dj = 0; dj < 3; ++dj) {
          const int ww = wp + dj - 1;
          const bool ok = hok && ((unsigned)ww < (unsigned)W_DIM);
          const float xv = ok ? xc[hh * W_DIM + ww] : 0.f;
          acc = fmaf(xv, wk[di * 3 + dj], acc);
        }
      }
      obase[(size_t)(i * G_DIM) * HW + p] = acc;
    }
  }
}

extern "C" void kernel_launch(void* const* d_in, const int* in_sizes, int n_in,
                              void* d_out, int out_size, void* d_ws, size_t ws_size,
                              hipStream_t stream) {
  const float* x  = (const float*)d_in[0];
  const float* wt = (const float*)d_in[1];
  float* out = (float*)d_out;

  dim3 grid(B_DIM * G_DIM, SLICES);   // 256 x 7 = 1792 blocks
  SKA_20950850470021_kernel<<<grid, 256, 0, stream>>>(x, wt, out);
}